// Round 1
// baseline (352.288 us; speedup 1.0000x reference)
//
#include <hip/hip_runtime.h>
#include <hip/hip_bf16.h>

typedef unsigned short u16;

#define BDIM 8
#define LDIM 8192
#define KDIM 256      // C
#define DDIM 256      // D
#define MTOT 65536    // B*L
#define NDIM 1536     // 6*D
#define TCH  128      // scan chunk length
#define NCH  64       // chunks per sequence (LDIM/TCH)

typedef float floatx4 __attribute__((ext_vector_type(4)));
typedef short bf16x8 __attribute__((ext_vector_type(8)));

__device__ __forceinline__ u16 f2bf(float f) {
  union { __hip_bfloat16 h; u16 u; } c;
  c.h = __float2bfloat16(f);
  return c.u;
}
__device__ __forceinline__ float bf2f(u16 u) {
  union { u16 u; __hip_bfloat16 h; } c;
  c.u = u;
  return __bfloat162float(c.h);
}
__device__ __forceinline__ float sigmoidf_fast(float x) {
  return __builtin_amdgcn_rcpf(1.0f + __expf(-x));
}

// ---------------------------------------------------------------------------
// Prep: WcatT[n][k] = W_g[k][n%256] as bf16, n-group order:
//   g0=Wh1, g1=Wz1, g2=Ws1, g3=Wh_1, g4=Wz_1, g5=Ws_1 ; bcat[n] = b_g[n%256]
// ---------------------------------------------------------------------------
__global__ void prep_weights(const float* __restrict__ Wh1, const float* __restrict__ Wz1,
                             const float* __restrict__ Ws1, const float* __restrict__ Wh_1,
                             const float* __restrict__ Wz_1, const float* __restrict__ Ws_1,
                             const float* __restrict__ bh1, const float* __restrict__ bz1,
                             const float* __restrict__ bs1, const float* __restrict__ bh_1,
                             const float* __restrict__ bz_1, const float* __restrict__ bs_1,
                             u16* __restrict__ WcatT, float* __restrict__ bcat) {
  const int n = blockIdx.x;       // 0..1535
  const int k = threadIdx.x;      // 0..255
  const int g = n >> 8, d = n & 255;
  const float* W; const float* bb;
  switch (g) {
    case 0: W = Wh1;  bb = bh1;  break;
    case 1: W = Wz1;  bb = bz1;  break;
    case 2: W = Ws1;  bb = bs1;  break;
    case 3: W = Wh_1; bb = bh_1; break;
    case 4: W = Wz_1; bb = bz_1; break;
    default: W = Ws_1; bb = bs_1; break;
  }
  WcatT[(size_t)n * KDIM + k] = f2bf(W[k * DDIM + d]);
  if (k == 0) bcat[n] = bb[d];
}

// ---------------------------------------------------------------------------
// Convert xs fp32 -> bf16 (read once from HBM; bf16 copy stays L3-resident
// across the 12 n-tile re-reads in the GEMM)
// ---------------------------------------------------------------------------
__global__ void convert_xs(const float* __restrict__ xs, u16* __restrict__ Abf) {
  size_t i = ((size_t)blockIdx.x * 256 + threadIdx.x) * 8;
  const float4* s = (const float4*)(xs + i);
  float4 f0 = s[0], f1 = s[1];
  union { u16 u[8]; uint4 v; } t;
  t.u[0] = f2bf(f0.x); t.u[1] = f2bf(f0.y); t.u[2] = f2bf(f0.z); t.u[3] = f2bf(f0.w);
  t.u[4] = f2bf(f1.x); t.u[5] = f2bf(f1.y); t.u[6] = f2bf(f1.z); t.u[7] = f2bf(f1.w);
  *(uint4*)(Abf + i) = t.v;
}

// ---------------------------------------------------------------------------
// GEMM: G[m][n] = sum_k Abf[m][k] * WcatT[n][k] + bcat[n], bf16 MFMA 16x16x32.
// 128x128 block tile, BK=32, 4 waves in 2x2, each wave 64x64 (4x4 mfma tiles).
// LDS quad-major layout: plane q holds k in [q*8, q*8+8), row-major rows,
// plane stride 1032 u16 (=2064 B -> bank offset 4/plane) for 2-way-max aliasing.
// ---------------------------------------------------------------------------
__global__ __launch_bounds__(256) void gemm_kernel(const u16* __restrict__ Abf,
                                                   const u16* __restrict__ WcatT,
                                                   const float* __restrict__ bcat,
                                                   u16* __restrict__ G) {
  __shared__ __align__(16) u16 As[4 * 1032];
  __shared__ __align__(16) u16 Bs[4 * 1032];
  const int tid = threadIdx.x;
  const int lane = tid & 63, wave = tid >> 6;
  const int wm = wave >> 1, wn = wave & 1;
  const int q = lane >> 4, r = lane & 15;
  const int m0 = blockIdx.y * 128, n0 = blockIdx.x * 128;
  const int row = tid >> 1, half = tid & 1;

  const u16* srcA = Abf + (size_t)(m0 + row) * KDIM + half * 16;
  const u16* srcB = WcatT + (size_t)(n0 + row) * KDIM + half * 16;
  u16* dstA0 = As + (2 * half) * 1032 + row * 8;
  u16* dstA1 = As + (2 * half + 1) * 1032 + row * 8;
  u16* dstB0 = Bs + (2 * half) * 1032 + row * 8;
  u16* dstB1 = Bs + (2 * half + 1) * 1032 + row * 8;

  floatx4 acc[4][4];
  floatx4 z4 = {0.f, 0.f, 0.f, 0.f};
#pragma unroll
  for (int i = 0; i < 4; i++)
#pragma unroll
    for (int j = 0; j < 4; j++) acc[i][j] = z4;

  for (int k0 = 0; k0 < KDIM; k0 += 32) {
    uint4 a0 = *(const uint4*)(srcA + k0);
    uint4 a1 = *(const uint4*)(srcA + k0 + 8);
    uint4 b0 = *(const uint4*)(srcB + k0);
    uint4 b1 = *(const uint4*)(srcB + k0 + 8);
    *(uint4*)dstA0 = a0;
    *(uint4*)dstA1 = a1;
    *(uint4*)dstB0 = b0;
    *(uint4*)dstB1 = b1;
    __syncthreads();
    bf16x8 af[4], bv[4];
#pragma unroll
    for (int i = 0; i < 4; i++)
      af[i] = *(const bf16x8*)(As + q * 1032 + (wm * 64 + i * 16 + r) * 8);
#pragma unroll
    for (int j = 0; j < 4; j++)
      bv[j] = *(const bf16x8*)(Bs + q * 1032 + (wn * 64 + j * 16 + r) * 8);
#pragma unroll
    for (int i = 0; i < 4; i++)
#pragma unroll
      for (int j = 0; j < 4; j++)
        acc[i][j] = __builtin_amdgcn_mfma_f32_16x16x32_bf16(af[i], bv[j], acc[i][j], 0, 0, 0);
    __syncthreads();
  }

  // Epilogue: C/D layout col = lane&15, row = (lane>>4)*4 + reg  [m89/m91]
  float bvals[4];
#pragma unroll
  for (int j = 0; j < 4; j++) bvals[j] = bcat[n0 + wn * 64 + j * 16 + r];
#pragma unroll
  for (int i = 0; i < 4; i++) {
#pragma unroll
    for (int reg = 0; reg < 4; reg++) {
      size_t grow = (size_t)(m0 + wm * 64 + i * 16 + q * 4 + reg);
      u16* dst = G + grow * NDIM + n0 + wn * 64 + r;
#pragma unroll
      for (int j = 0; j < 4; j++)
        dst[j * 16] = f2bf(acc[i][j][reg] + bvals[j]);
    }
  }
}

// ---------------------------------------------------------------------------
// Scan phase A: per-chunk affine summary. h[t] = a*h + z*gh, a = 1-z.
// dir 0: fwd (ascending t, cols h@0 z@256). dir 1: bwd (descending t, h@768 z@1024).
// ---------------------------------------------------------------------------
__global__ void scan_phaseA(const u16* __restrict__ G, float* __restrict__ Acc,
                            float* __restrict__ Bcc) {
  const int d = threadIdx.x, c = blockIdx.x, b = blockIdx.y, dir = blockIdx.z;
  const int hoff = dir ? 768 : 0, zoff = hoff + 256;
  const size_t base = (size_t)b * LDIM * NDIM;
  float h = 0.f, P = 1.f;
#pragma unroll 4
  for (int i = 0; i < TCH; ++i) {
    int t = dir ? (c * TCH + (TCH - 1 - i)) : (c * TCH + i);
    size_t off = base + (size_t)t * NDIM;
    float gh = bf2f(G[off + hoff + d]);
    float gz = bf2f(G[off + zoff + d]);
    float z = sigmoidf_fast(gz);
    float a = 1.f - z;
    h = fmaf(a, h, z * gh);
    P *= a;
  }
  size_t idx = (((size_t)dir * BDIM + b) * NCH + c) * DDIM + d;
  Acc[idx] = P;
  Bcc[idx] = h;
}

// ---------------------------------------------------------------------------
// Scan phase B: chain chunk summaries -> per-chunk entering prefix.
// ---------------------------------------------------------------------------
__global__ void scan_phaseB(const float* __restrict__ Acc, const float* __restrict__ Bcc,
                            const float* __restrict__ h01, const float* __restrict__ h0_1,
                            float* __restrict__ Pref) {
  const int d = threadIdx.x, b = blockIdx.x, dir = blockIdx.y;
  float h = dir ? h0_1[d] : h01[d];
  if (dir == 0) {
    for (int c = 0; c < NCH; ++c) {
      size_t idx = ((size_t)b * NCH + c) * DDIM + d;
      Pref[idx] = h;
      h = fmaf(Acc[idx], h, Bcc[idx]);
    }
  } else {
    for (int c = NCH - 1; c >= 0; --c) {
      size_t idx = (((size_t)BDIM + b) * NCH + c) * DDIM + d;
      Pref[idx] = h;
      h = fmaf(Acc[idx], h, Bcc[idx]);
    }
  }
}

// ---------------------------------------------------------------------------
// Scan phase C fwd: replay chunk with prefix, out = h * sigmoid(gs_f)
// ---------------------------------------------------------------------------
__global__ void scan_phaseC_fwd(const u16* __restrict__ G, const float* __restrict__ Pref,
                                float* __restrict__ out) {
  const int d = threadIdx.x, c = blockIdx.x, b = blockIdx.y;
  float h = Pref[((size_t)b * NCH + c) * DDIM + d];
  const size_t base = (size_t)b * LDIM * NDIM;
#pragma unroll 4
  for (int i = 0; i < TCH; ++i) {
    int t = c * TCH + i;
    size_t off = base + (size_t)t * NDIM;
    float gh = bf2f(G[off + 0 + d]);
    float gz = bf2f(G[off + 256 + d]);
    float gs = bf2f(G[off + 512 + d]);
    float z = sigmoidf_fast(gz);
    h = fmaf(1.f - z, h, z * gh);
    out[((size_t)b * LDIM + t) * DDIM + d] = h * sigmoidf_fast(gs);
  }
}

// ---------------------------------------------------------------------------
// Scan phase C bwd: descending replay, out += h * sigmoid(gs_b)
// (separate kernel after fwd -> stream-ordered, no RMW race)
// ---------------------------------------------------------------------------
__global__ void scan_phaseC_bwd(const u16* __restrict__ G, const float* __restrict__ Pref,
                                float* __restrict__ out) {
  const int d = threadIdx.x, c = blockIdx.x, b = blockIdx.y;
  float h = Pref[(((size_t)BDIM + b) * NCH + c) * DDIM + d];
  const size_t base = (size_t)b * LDIM * NDIM;
#pragma unroll 4
  for (int i = 0; i < TCH; ++i) {
    int t = c * TCH + (TCH - 1 - i);
    size_t off = base + (size_t)t * NDIM;
    float gh = bf2f(G[off + 768 + d]);
    float gz = bf2f(G[off + 1024 + d]);
    float gs = bf2f(G[off + 1280 + d]);
    float z = sigmoidf_fast(gz);
    h = fmaf(1.f - z, h, z * gh);
    float* op = out + ((size_t)b * LDIM + t) * DDIM + d;
    *op = *op + h * sigmoidf_fast(gs);
  }
}

extern "C" void kernel_launch(void* const* d_in, const int* in_sizes, int n_in,
                              void* d_out, int out_size, void* d_ws, size_t ws_size,
                              hipStream_t stream) {
  const float* xs   = (const float*)d_in[0];
  const float* Wh1  = (const float*)d_in[1];
  const float* bh1  = (const float*)d_in[2];
  const float* Wz1  = (const float*)d_in[3];
  const float* bz1  = (const float*)d_in[4];
  const float* Ws1  = (const float*)d_in[5];
  const float* bs1  = (const float*)d_in[6];
  const float* h01  = (const float*)d_in[7];
  const float* Wh_1 = (const float*)d_in[8];
  const float* bh_1 = (const float*)d_in[9];
  const float* Wz_1 = (const float*)d_in[10];
  const float* bz_1 = (const float*)d_in[11];
  const float* Ws_1 = (const float*)d_in[12];
  const float* bs_1 = (const float*)d_in[13];
  const float* h0_1 = (const float*)d_in[14];
  float* out = (float*)d_out;

  char* ws = (char*)d_ws;
  u16* WcatT = (u16*)ws;            ws += (size_t)NDIM * KDIM * 2;          // 0.75 MB
  float* bcat = (float*)ws;         ws += (size_t)NDIM * 4;                 // 6 KB
  u16* Abf = (u16*)ws;              ws += (size_t)MTOT * KDIM * 2;          // 32 MB
  u16* G = (u16*)ws;                ws += (size_t)MTOT * NDIM * 2;          // 192 MB
  float* Acc = (float*)ws;          ws += (size_t)2 * BDIM * NCH * DDIM * 4;
  float* Bcc = (float*)ws;          ws += (size_t)2 * BDIM * NCH * DDIM * 4;
  float* Pref = (float*)ws;         ws += (size_t)2 * BDIM * NCH * DDIM * 4;
  if ((size_t)(ws - (char*)d_ws) > ws_size) return;  // workspace too small

  prep_weights<<<dim3(NDIM), dim3(KDIM), 0, stream>>>(
      Wh1, Wz1, Ws1, Wh_1, Wz_1, Ws_1, bh1, bz1, bs1, bh_1, bz_1, bs_1, WcatT, bcat);
  convert_xs<<<dim3(MTOT * KDIM / (256 * 8)), dim3(256), 0, stream>>>(xs, Abf);
  gemm_kernel<<<dim3(NDIM / 128, MTOT / 128), dim3(256), 0, stream>>>(Abf, WcatT, bcat, G);
  scan_phaseA<<<dim3(NCH, BDIM, 2), dim3(DDIM), 0, stream>>>(G, Acc, Bcc);
  scan_phaseB<<<dim3(BDIM, 2), dim3(DDIM), 0, stream>>>(Acc, Bcc, h01, h0_1, Pref);
  scan_phaseC_fwd<<<dim3(NCH, BDIM), dim3(DDIM), 0, stream>>>(G, Pref, out);
  scan_phaseC_bwd<<<dim3(NCH, BDIM), dim3(DDIM), 0, stream>>>(G, Pref, out);
}